// Round 4
// baseline (954.316 us; speedup 1.0000x reference)
//
#include <hip/hip_runtime.h>
#include <hip/hip_bf16.h>
#include <hip/hip_fp8.h>

typedef int i32x8 __attribute__((ext_vector_type(8)));
typedef int i32x4 __attribute__((ext_vector_type(4)));
typedef float f32x4 __attribute__((ext_vector_type(4)));
typedef unsigned char uchar_t;

constexpr int NB = 32768;   // batch rows
constexpr int D1 = 1024;    // K
constexpr int D2 = 4096;    // N
constexpr float BETA_LOG2E = 14.4269504088896340736f; // 10 * log2(e)
constexpr float SCALE_A = 16.0f;        // g1 pre-scale into e4m3 sweet range
constexpr float SCALE_B = 8192.0f;      // dW pre-scale (dW ~ 0.003*N)
constexpr float INV_SCALE = 1.0f / (16.0f * 8192.0f);  // 2^-17

__device__ __forceinline__ uchar_t f32_to_fp8(float f) {
  __hip_fp8_e4m3 q(f);                  // OCP e4m3fn, RNE+satfinite
  return (uchar_t)q.__x;
}

__device__ __forceinline__ void async_copy16(const void* g, void* l) {
  __builtin_amdgcn_global_load_lds(
      (const __attribute__((address_space(1))) void*)g,
      (__attribute__((address_space(3))) void*)l, 16, 0, 0);
}

// ---- 1. column stats of W: sq[j] += sum_k W^2 ; colsum[j] += sum_k W ----
__global__ void colstats(const float* __restrict__ W, float* __restrict__ sq,
                         float* __restrict__ colsum) {
  int j = blockIdx.x * 256 + threadIdx.x;   // gridDim.x = 16
  int k0 = blockIdx.y * 64;                 // gridDim.y = 16
  float a = 0.f, b = 0.f;
#pragma unroll 8
  for (int k = 0; k < 64; ++k) {
    float w = W[(size_t)(k0 + k) * D2 + j];
    a += w * w; b += w;
  }
  atomicAdd(&sq[j], a);
  atomicAdd(&colsum[j], b);
}

// ---- 2. mean-subtracted normalize + transpose to fp8:
// mu[j] = colsum[j]*inv/1024; B8t[j][k] = fp8((W[k][j]*inv - mu[j]) * SCALE_B)
__global__ void convert_b(const float* __restrict__ W, const float* __restrict__ sq,
                          const float* __restrict__ colsum,
                          uchar_t* __restrict__ B8t, float* __restrict__ mu) {
  __shared__ float tile[64][65];
  int t = threadIdx.x;                 // 256
  int j0 = blockIdx.x * 64;            // gridDim.x = 64
  int k0 = blockIdx.y * 64;            // gridDim.y = 16
  int c = t & 63, r4 = t >> 6;
#pragma unroll
  for (int s = 0; s < 16; ++s) {
    int k = s * 4 + r4;
    tile[k][c] = W[(size_t)(k0 + k) * D2 + j0 + c];
  }
  __syncthreads();
#pragma unroll
  for (int s = 0; s < 16; ++s) {
    int jj = s * 4 + r4;
    float inv = 1.0f / sqrtf(sq[j0 + jj]);
    float muj = colsum[j0 + jj] * inv * (1.0f / 1024.0f);
    if (k0 == 0 && c == 0) mu[j0 + jj] = muj;
    float dw = tile[c][jj] * inv - muj;
    B8t[(size_t)(j0 + jj) * D1 + k0 + c] = f32_to_fp8(dw * SCALE_B);
  }
}

// ---- 3. g1 fp32 -> fp8 (x16) + row sums. Wave-per-row, grid-stride. ----
__global__ __launch_bounds__(256)
void convert_a(const float* __restrict__ g1, uchar_t* __restrict__ A8,
               float* __restrict__ S) {
  const int lane = threadIdx.x & 63;
  const int gw = (blockIdx.x * 256 + threadIdx.x) >> 6;  // 8192 waves
  for (int row = gw; row < NB; row += 8192) {
    const float* src = g1 + (size_t)row * D1 + lane * 16;
    float v[16];
    *(float4*)(v)      = ((const float4*)src)[0];
    *(float4*)(v + 4)  = ((const float4*)src)[1];
    *(float4*)(v + 8)  = ((const float4*)src)[2];
    *(float4*)(v + 12) = ((const float4*)src)[3];
    float sum = 0.f;
    union { uchar_t b[16]; uint4 u; } o;
#pragma unroll
    for (int j = 0; j < 16; ++j) { sum += v[j]; o.b[j] = f32_to_fp8(v[j] * SCALE_A); }
    *(uint4*)(A8 + (size_t)row * D1 + lane * 16) = o.u;
#pragma unroll
    for (int m = 1; m < 64; m <<= 1) sum += __shfl_xor(sum, m, 64);
    if (lane == 0) S[row] = sum;
  }
}

// ---- 4. fused fp8 GEMM + exp-sum, 256x256 tile, 512 thr = 8 waves (2M x 4N),
// counted-vmcnt 3-phase schedule (correctness proven R2/R3).
//
// R4: 2D-CHUNKED XCD OWNERSHIP. R2 (2col x 16row co-res) and R3 (2row x 16col)
// both put 4.5 MiB in a 4 MiB per-XCD L2 -> LRU cliff -> ZERO reuse (FETCH
// 1.04-1.09 GB = exact zero-reuse model, both rounds). Fix: XCD x owns
// row-half (x>>2, 64 row-blocks) x col-quad (x&3, 4 col-blocks), cols fastest.
// Co-resident window (32 blocks = 1/CU x 32 CU/XCD) = 8 rows x 4 cols:
// working set = 8x256K A + 4x256K B = 3 MiB = 75% of L2 (headroom).
// Each A-panel's 4 col-consumers are adjacent in dispatch order; the XCD's
// 1 MiB B-slice is touched by every block -> pinned by LRU for the kernel's
// lifetime. Ideal HBM: A 16 MiB/XCD x 8 + B 8 MB ~= 140 MB (was 2.34 GB).
__global__ __launch_bounds__(512, 2)
void gemm_expsum(const uchar_t* __restrict__ A8, const uchar_t* __restrict__ B8t,
                 const float* __restrict__ S, const float* __restrict__ mu,
                 float* __restrict__ s) {
  __shared__ __align__(16) uchar_t As[2 * 256 * 128];  // 64 KiB
  __shared__ __align__(16) uchar_t Bs[2 * 256 * 128];  // 64 KiB

  // 2048 blocks; hardware round-robins bid across 8 XCDs (xcd = bid & 7).
  const int bid = blockIdx.x;
  const int xcd = bid & 7;
  const int l   = bid >> 3;            // 0..255 local sequence on this XCD
  const int rq  = l >> 2;              // 0..63  row-block within the half
  const int cq  = l & 3;               // 0..3   col-block within the quad (fastest)
  const int row0 = ((xcd >> 2) * 64 + rq) * 256;
  const int col0 = ((xcd & 3) * 4 + cq) * 256;

  const int t = threadIdx.x;
  const int lane = t & 63;
  const int wave = t >> 6;
  const int wm = (wave >> 2) * 128;    // 2 M-groups
  const int wn = (wave & 3) * 64;      // 4 N-groups
  const int llo = lane & 15, lhi = lane >> 4;

  f32x4 acc[8][4] = {};

  // staging geometry: thread t -> local row r = t>>3, seg = t&7; fetches
  // global segment seg^(r&7) so the LINEAR LDS write lands swizzled.
  const int r   = t >> 3;
  const int rB  = ((r >> 5) << 6) + (r & 31);   // B-unit base rows {0-31,64-95}
  const int seg = t & 7;
  const int swz = seg ^ (r & 7);
  const uchar_t* gA = A8  + (size_t)(row0 + r ) * D1 + swz * 16;
  const uchar_t* gB = B8t + (size_t)(col0 + rB) * D1 + swz * 16;
  uchar_t* lA = As + r  * 128 + seg * 16;
  uchar_t* lB = Bs + rB * 128 + seg * 16;

#define ISSUE_A0(kt, bo) { async_copy16(gA + (kt),              lA + (bo)); \
                           async_copy16(gA + (kt) + 128 * 1024, lA + (bo) + 128 * 128); }
#define ISSUE_B0(kt, bo) { async_copy16(gB + (kt),              lB + (bo)); \
                           async_copy16(gB + (kt) + 128 * 1024, lB + (bo) + 128 * 128); }
#define ISSUE_B1(kt, bo) { async_copy16(gB + (kt) +  32 * 1024, lB + (bo) +  32 * 128); \
                           async_copy16(gB + (kt) + 160 * 1024, lB + (bo) + 160 * 128); }
#define ISSUE_A1(kt, bo) { async_copy16(gA + (kt) +  64 * 1024, lA + (bo) +  64 * 128); \
                           async_copy16(gA + (kt) + 192 * 1024, lA + (bo) + 192 * 128); }

  // lane's fragment k-window lhi*32..+31 = two 16B segs at swizzled slots
  const int sw0 = ((lhi * 2 + 0) ^ (llo & 7)) * 16;
  const int sw1 = ((lhi * 2 + 1) ^ (llo & 7)) * 16;

  // prologue: tile 0 into buf 0 (issue order defines vmcnt age order)
  ISSUE_A0(0, 0); ISSUE_B0(0, 0); ISSUE_B1(0, 0); ISSUE_A1(0, 0);
  asm volatile("s_waitcnt vmcnt(4)" ::: "memory");   // A0,B0 landed; B1,A1 fly
  __builtin_amdgcn_s_barrier();

  for (int T = 0; T < 8; ++T) {
    const int p = T & 1;
    const int kt1 = ((T + 1) & 7) * 128;   // wraps to 0 on last iter (dummy,
                                           // L2-hot after locality fix)
    const int bo1 = (p ^ 1) * 32768;
    const uchar_t* baseA = As + p * 32768;
    const uchar_t* baseB = Bs + p * 32768;
    i32x8 af[4], bq[4];

    // ---------- P1: mh=0, nh=0 ----------
    ISSUE_A0(kt1, bo1); ISSUE_B0(kt1, bo1);
#pragma unroll
    for (int q = 0; q < 4; ++q) {
      const uchar_t* a = baseA + (wm + q * 16 + llo) * 128;
      i32x4 h0 = *(const i32x4*)(a + sw0);
      i32x4 h1 = *(const i32x4*)(a + sw1);
      af[q] = __builtin_shufflevector(h0, h1, 0, 1, 2, 3, 4, 5, 6, 7);
    }
#pragma unroll
    for (int j = 0; j < 2; ++j) {
      const uchar_t* b = baseB + (wn + j * 16 + llo) * 128;
      i32x4 h0 = *(const i32x4*)(b + sw0);
      i32x4 h1 = *(const i32x4*)(b + sw1);
      bq[j] = __builtin_shufflevector(h0, h1, 0, 1, 2, 3, 4, 5, 6, 7);
    }
    __builtin_amdgcn_s_setprio(1);
#pragma unroll
    for (int q = 0; q < 4; ++q)
#pragma unroll
      for (int j = 0; j < 2; ++j)
        acc[q][j] = __builtin_amdgcn_mfma_scale_f32_16x16x128_f8f6f4(
            af[q], bq[j], acc[q][j], 0, 0, 0, 127, 0, 127);
    __builtin_amdgcn_s_setprio(0);
    asm volatile("s_waitcnt vmcnt(6)" ::: "memory");  // T.B1 landed
    __builtin_amdgcn_s_barrier();

    // ---------- P2: mh=0, nh=1 ----------
    ISSUE_B1(kt1, bo1);
#pragma unroll
    for (int j = 0; j < 2; ++j) {
      const uchar_t* b = baseB + (wn + (2 + j) * 16 + llo) * 128;
      i32x4 h0 = *(const i32x4*)(b + sw0);
      i32x4 h1 = *(const i32x4*)(b + sw1);
      bq[2 + j] = __builtin_shufflevector(h0, h1, 0, 1, 2, 3, 4, 5, 6, 7);
    }
    __builtin_amdgcn_s_setprio(1);
#pragma unroll
    for (int q = 0; q < 4; ++q)
#pragma unroll
      for (int j = 0; j < 2; ++j)
        acc[q][2 + j] = __builtin_amdgcn_mfma_scale_f32_16x16x128_f8f6f4(
            af[q], bq[2 + j], acc[q][2 + j], 0, 0, 0, 127, 0, 127);
    __builtin_amdgcn_s_setprio(0);
    asm volatile("s_waitcnt vmcnt(6)" ::: "memory");  // T.A1 landed
    __builtin_amdgcn_s_barrier();

    // ---------- P3: mh=1, all nh ----------
    ISSUE_A1(kt1, bo1);
#pragma unroll
    for (int q = 0; q < 4; ++q) {
      const uchar_t* a = baseA + (wm + 64 + q * 16 + llo) * 128;
      i32x4 h0 = *(const i32x4*)(a + sw0);
      i32x4 h1 = *(const i32x4*)(a + sw1);
      af[q] = __builtin_shufflevector(h0, h1, 0, 1, 2, 3, 4, 5, 6, 7);
    }
    __builtin_amdgcn_s_setprio(1);
#pragma unroll
    for (int q = 0; q < 4; ++q)
#pragma unroll
      for (int j = 0; j < 4; ++j)
        acc[4 + q][j] = __builtin_amdgcn_mfma_scale_f32_16x16x128_f8f6f4(
            af[q], bq[j], acc[4 + q][j], 0, 0, 0, 127, 0, 127);
    __builtin_amdgcn_s_setprio(0);
    asm volatile("s_waitcnt vmcnt(4)" ::: "memory");  // T1.{A0,B0} landed; 4 fly
    __builtin_amdgcn_s_barrier();
  }
#undef ISSUE_A0
#undef ISSUE_B0
#undef ISSUE_B1
#undef ISSUE_A1

  // epilogue: x2 = mu_j*S_b + acc*2^-17; per-row sum of exp2(x2*beta*log2e).
  // C/D layout (16x16): col = lane&15, row = (lane>>4)*4 + reg.
  float muv[4];
#pragma unroll
  for (int ni = 0; ni < 4; ++ni) muv[ni] = mu[col0 + wn + ni * 16 + llo];

#pragma unroll
  for (int mi = 0; mi < 8; ++mi) {
    const int row = row0 + wm + mi * 16 + lhi * 4;
    float4 sv = *(const float4*)(S + row);
    float sarr[4] = {sv.x, sv.y, sv.z, sv.w};
    float rs[4];
#pragma unroll
    for (int rr = 0; rr < 4; ++rr) {
      float v = 0.f;
#pragma unroll
      for (int ni = 0; ni < 4; ++ni) {
        float x2 = fmaf(acc[mi][ni][rr], INV_SCALE, muv[ni] * sarr[rr]);
        v += exp2f(x2 * BETA_LOG2E);
      }
      rs[rr] = v;
    }
#pragma unroll
    for (int m = 1; m < 16; m <<= 1) {
#pragma unroll
      for (int rr = 0; rr < 4; ++rr)
        rs[rr] += __shfl_xor(rs[rr], m, 64);
    }
    if (llo == 0) {
#pragma unroll
      for (int rr = 0; rr < 4; ++rr)
        atomicAdd(&s[row + rr], rs[rr]);
    }
  }
}

// ---- 5. out[b] = -(1/beta) * log(s[b]) ----
__global__ void finish_kernel(const float* __restrict__ s, float* __restrict__ out) {
  int b = blockIdx.x * 256 + threadIdx.x;
  out[b] = -0.1f * logf(s[b]);
}

extern "C" void kernel_launch(void* const* d_in, const int* in_sizes, int n_in,
                              void* d_out, int out_size, void* d_ws, size_t ws_size,
                              hipStream_t stream) {
  const float* g1 = (const float*)d_in[0];
  const float* W  = (const float*)d_in[1];
  float* out = (float*)d_out;

  char* ws = (char*)d_ws;
  float* s       = (float*)ws;                    // 32768*4 = 131072
  float* sq      = (float*)(ws + 131072);         // 4096*4
  float* colsum  = (float*)(ws + 147456);         // 4096*4
  float* mu      = (float*)(ws + 163840);         // 4096*4
  float* S       = (float*)(ws + 180224);         // 32768*4
  uchar_t* A8    = (uchar_t*)(ws + 311296);       // 32 MiB
  uchar_t* B8t   = (uchar_t*)(ws + 311296 + 33554432);  // 4 MiB

  hipMemsetAsync(ws, 0, 180224, stream);  // zero s, sq, colsum

  colstats<<<dim3(16, 16), 256, 0, stream>>>(W, sq, colsum);
  convert_b<<<dim3(64, 16), 256, 0, stream>>>(W, sq, colsum, B8t, mu);
  convert_a<<<dim3(2048), 256, 0, stream>>>(g1, A8, S);
  gemm_expsum<<<dim3(2048), 512, 0, stream>>>(A8, B8t, S, mu, s);
  finish_kernel<<<dim3(128), 256, 0, stream>>>(s, out);
}

// Round 5
// 440.342 us; speedup vs baseline: 2.1672x; 2.1672x over previous
//
#include <hip/hip_runtime.h>
#include <hip/hip_bf16.h>
#include <hip/hip_fp8.h>

typedef int i32x8 __attribute__((ext_vector_type(8)));
typedef int i32x4 __attribute__((ext_vector_type(4)));
typedef float f32x4 __attribute__((ext_vector_type(4)));
typedef unsigned char uchar_t;

constexpr int NB = 32768;   // batch rows
constexpr int D1 = 1024;    // K
constexpr int D2 = 4096;    // N
constexpr float BETA_LOG2E = 14.4269504088896340736f; // 10 * log2(e)
constexpr float SCALE_A = 16.0f;        // g1 pre-scale into e4m3 sweet range
constexpr float SCALE_B = 8192.0f;      // dW pre-scale (dW ~ 0.003*N)
constexpr float INV_SCALE = 1.0f / (16.0f * 8192.0f);  // 2^-17

__device__ __forceinline__ uchar_t f32_to_fp8(float f) {
  __hip_fp8_e4m3 q(f);                  // OCP e4m3fn, RNE+satfinite
  return (uchar_t)q.__x;
}

__device__ __forceinline__ void async_copy16(const void* g, void* l) {
  __builtin_amdgcn_global_load_lds(
      (const __attribute__((address_space(1))) void*)g,
      (__attribute__((address_space(3))) void*)l, 16, 0, 0);
}

// ---- 1. column stats of W: sq[j] += sum_k W^2 ; colsum[j] += sum_k W ----
__global__ void colstats(const float* __restrict__ W, float* __restrict__ sq,
                         float* __restrict__ colsum) {
  int j = blockIdx.x * 256 + threadIdx.x;   // gridDim.x = 16
  int k0 = blockIdx.y * 64;                 // gridDim.y = 16
  float a = 0.f, b = 0.f;
#pragma unroll 8
  for (int k = 0; k < 64; ++k) {
    float w = W[(size_t)(k0 + k) * D2 + j];
    a += w * w; b += w;
  }
  atomicAdd(&sq[j], a);
  atomicAdd(&colsum[j], b);
}

// ---- 2. mean-subtracted normalize + transpose to fp8:
// mu[j] = colsum[j]*inv/1024; B8t[j][k] = fp8((W[k][j]*inv - mu[j]) * SCALE_B)
__global__ void convert_b(const float* __restrict__ W, const float* __restrict__ sq,
                          const float* __restrict__ colsum,
                          uchar_t* __restrict__ B8t, float* __restrict__ mu) {
  __shared__ float tile[64][65];
  int t = threadIdx.x;                 // 256
  int j0 = blockIdx.x * 64;            // gridDim.x = 64
  int k0 = blockIdx.y * 64;            // gridDim.y = 16
  int c = t & 63, r4 = t >> 6;
#pragma unroll
  for (int s = 0; s < 16; ++s) {
    int k = s * 4 + r4;
    tile[k][c] = W[(size_t)(k0 + k) * D2 + j0 + c];
  }
  __syncthreads();
#pragma unroll
  for (int s = 0; s < 16; ++s) {
    int jj = s * 4 + r4;
    float inv = 1.0f / sqrtf(sq[j0 + jj]);
    float muj = colsum[j0 + jj] * inv * (1.0f / 1024.0f);
    if (k0 == 0 && c == 0) mu[j0 + jj] = muj;
    float dw = tile[c][jj] * inv - muj;
    B8t[(size_t)(j0 + jj) * D1 + k0 + c] = f32_to_fp8(dw * SCALE_B);
  }
}

// ---- 3. g1 fp32 -> fp8 (x16) + row sums. Wave-per-row, grid-stride. ----
__global__ __launch_bounds__(256)
void convert_a(const float* __restrict__ g1, uchar_t* __restrict__ A8,
               float* __restrict__ S) {
  const int lane = threadIdx.x & 63;
  const int gw = (blockIdx.x * 256 + threadIdx.x) >> 6;  // 8192 waves
  for (int row = gw; row < NB; row += 8192) {
    const float* src = g1 + (size_t)row * D1 + lane * 16;
    float v[16];
    *(float4*)(v)      = ((const float4*)src)[0];
    *(float4*)(v + 4)  = ((const float4*)src)[1];
    *(float4*)(v + 8)  = ((const float4*)src)[2];
    *(float4*)(v + 12) = ((const float4*)src)[3];
    float sum = 0.f;
    union { uchar_t b[16]; uint4 u; } o;
#pragma unroll
    for (int j = 0; j < 16; ++j) { sum += v[j]; o.b[j] = f32_to_fp8(v[j] * SCALE_A); }
    *(uint4*)(A8 + (size_t)row * D1 + lane * 16) = o.u;
#pragma unroll
    for (int m = 1; m < 64; m <<= 1) sum += __shfl_xor(sum, m, 64);
    if (lane == 0) S[row] = sum;
  }
}

// ---- 4. fused fp8 GEMM + exp-sum.
// R5: R0's PROVEN GEOMETRY (128x128 tile, dim3(32,256) x=col-fast, 256 thr =
// 4 waves 2x2, 64 KiB LDS dbuf, 2 blocks/CU -> FETCH was 133 MB, i.e. near-
// ideal L2 reuse under the real dispatch policy) + the counted-vmcnt schedule
// R0 lacked (R0: one vmcnt(0)-draining barrier per K-iter -> MfmaUtil 26%).
// R2-R4's 256^2 tile variants all thrashed L2 (FETCH ~1 GB, zero reuse) under
// every XCD-mapping guess; mapping is undefined -> stop inverting it, keep the
// geometry that measured well.
//
// COUNTED-VMCNT 2-PHASE SCHEDULE per K-tile (BK=128B), units per thread:
//   U_A  = 4 loads (A rows 0-127; all af needed in P1)
//   U_B0 = 2 loads (B rows {0-31,64-95}:  bq[0..1], output cols wn..wn+31)
//   U_B1 = 2 loads (B rows {32-63,96-127}: bq[2..3])
// Steady state (tile T in buf p, T+1 staged into buf p^1):
//   P1: issue T1.{A,B0} (6) -> out = T.B1(2)+6 = 8; read af x4, bq01; 8 MFMA;
//       vmcnt(6) => T.B1 landed; barrier.
//   P2: issue T1.B1 (2) -> out = 8; read bq23; 8 MFMA;
//       vmcnt(2) => T1.{A,B0} landed, T1.B1 STAYS IN FLIGHT across barrier.
// Never vmcnt(0) in-loop. Last iter issues wrap-around dummies (L2-hot) so
// vmcnt literals are iteration-invariant.
__global__ __launch_bounds__(256, 2)
void gemm_expsum(const uchar_t* __restrict__ A8, const uchar_t* __restrict__ B8t,
                 const float* __restrict__ S, const float* __restrict__ mu,
                 float* __restrict__ s) {
  __shared__ __align__(16) uchar_t As[2 * 128 * 128];  // 32 KiB
  __shared__ __align__(16) uchar_t Bs[2 * 128 * 128];  // 32 KiB

  const int t = threadIdx.x;
  const int row0 = blockIdx.y * 128;   // gridDim.y = 256
  const int col0 = blockIdx.x * 128;   // gridDim.x = 32 (fast axis, R0-proven)
  const int lane = t & 63;
  const int wave = t >> 6;
  const int wm = (wave >> 1) * 64;
  const int wn = (wave & 1) * 64;
  const int llo = lane & 15, lhi = lane >> 4;

  f32x4 acc[4][4] = {};

  // staging: thread t owns LDS slot (row=t>>3, seg=t&7); fetches global
  // segment (t&7)^(row&7). Sweep i advances row by 32 (row&7 invariant).
  const int srow = t >> 3;
  const int sseg = (t & 7) ^ (srow & 7);
  const uchar_t* gA = A8  + (size_t)(row0 + srow) * D1 + sseg * 16;
  const uchar_t* gB = B8t + (size_t)(col0 + srow) * D1 + sseg * 16;

  // U_A: sweeps 0-3 (A rows 0-127). U_B0: sweeps 0,2. U_B1: sweeps 1,3.
#define ISSUE_A(kt, bo)  { async_copy16(gA + (kt),             As + (bo) + t * 16); \
                           async_copy16(gA + (kt) + 32 * 1024, As + (bo) + t * 16 + 4096); \
                           async_copy16(gA + (kt) + 64 * 1024, As + (bo) + t * 16 + 8192); \
                           async_copy16(gA + (kt) + 96 * 1024, As + (bo) + t * 16 + 12288); }
#define ISSUE_B0(kt, bo) { async_copy16(gB + (kt),             Bs + (bo) + t * 16); \
                           async_copy16(gB + (kt) + 64 * 1024, Bs + (bo) + t * 16 + 8192); }
#define ISSUE_B1(kt, bo) { async_copy16(gB + (kt) + 32 * 1024, Bs + (bo) + t * 16 + 4096); \
                           async_copy16(gB + (kt) + 96 * 1024, Bs + (bo) + t * 16 + 12288); }

  // lane's fragment: row m=llo(+16*q), k-window lhi*32..+31 = two 16B segs,
  // stored swizzled at seg (lhi*2+h)^(llo&7)
  const int sw0 = ((lhi * 2 + 0) ^ (llo & 7)) * 16;
  const int sw1 = ((lhi * 2 + 1) ^ (llo & 7)) * 16;

  // prologue: tile 0 into buf 0; A+B0 landed, B1 in flight
  ISSUE_A(0, 0); ISSUE_B0(0, 0); ISSUE_B1(0, 0);
  asm volatile("s_waitcnt vmcnt(2)" ::: "memory");
  __builtin_amdgcn_s_barrier();

  for (int T = 0; T < 8; ++T) {
    const int p = T & 1;
    const int kt1 = ((T + 1) & 7) * 128;   // wraps to 0 on last iter (dummy)
    const int bo1 = (p ^ 1) * 16384;
    const uchar_t* baseA = As + p * 16384;
    const uchar_t* baseB = Bs + p * 16384;
    i32x8 af[4], bq[4];

    // ---------- P1: all af, bq[0..1] ----------
    ISSUE_A(kt1, bo1); ISSUE_B0(kt1, bo1);
#pragma unroll
    for (int q = 0; q < 4; ++q) {
      const uchar_t* a = baseA + (wm + q * 16 + llo) * 128;
      i32x4 h0 = *(const i32x4*)(a + sw0);
      i32x4 h1 = *(const i32x4*)(a + sw1);
      af[q] = __builtin_shufflevector(h0, h1, 0, 1, 2, 3, 4, 5, 6, 7);
    }
#pragma unroll
    for (int j = 0; j < 2; ++j) {
      const uchar_t* b = baseB + (wn + j * 16 + llo) * 128;
      i32x4 h0 = *(const i32x4*)(b + sw0);
      i32x4 h1 = *(const i32x4*)(b + sw1);
      bq[j] = __builtin_shufflevector(h0, h1, 0, 1, 2, 3, 4, 5, 6, 7);
    }
    __builtin_amdgcn_s_setprio(1);
#pragma unroll
    for (int q = 0; q < 4; ++q)
#pragma unroll
      for (int j = 0; j < 2; ++j)
        acc[q][j] = __builtin_amdgcn_mfma_scale_f32_16x16x128_f8f6f4(
            af[q], bq[j], acc[q][j], 0, 0, 0, 127, 0, 127);
    __builtin_amdgcn_s_setprio(0);
    asm volatile("s_waitcnt vmcnt(6)" ::: "memory");  // T.B1 landed
    __builtin_amdgcn_s_barrier();

    // ---------- P2: af x bq[2..3] ----------
    ISSUE_B1(kt1, bo1);
#pragma unroll
    for (int j = 2; j < 4; ++j) {
      const uchar_t* b = baseB + (wn + j * 16 + llo) * 128;
      i32x4 h0 = *(const i32x4*)(b + sw0);
      i32x4 h1 = *(const i32x4*)(b + sw1);
      bq[j] = __builtin_shufflevector(h0, h1, 0, 1, 2, 3, 4, 5, 6, 7);
    }
    __builtin_amdgcn_s_setprio(1);
#pragma unroll
    for (int q = 0; q < 4; ++q)
#pragma unroll
      for (int j = 2; j < 4; ++j)
        acc[q][j] = __builtin_amdgcn_mfma_scale_f32_16x16x128_f8f6f4(
            af[q], bq[j], acc[q][j], 0, 0, 0, 127, 0, 127);
    __builtin_amdgcn_s_setprio(0);
    asm volatile("s_waitcnt vmcnt(2)" ::: "memory");  // T1.{A,B0} landed; 2 fly
    __builtin_amdgcn_s_barrier();
  }
#undef ISSUE_A
#undef ISSUE_B0
#undef ISSUE_B1

  // epilogue: x2 = mu_j*S_b + acc*2^-17; per-row sum of exp2(x2*beta*log2e).
  // C/D layout (16x16): col = lane&15, row = (lane>>4)*4 + reg.
  float muv[4];
#pragma unroll
  for (int ni = 0; ni < 4; ++ni) muv[ni] = mu[col0 + wn + ni * 16 + llo];

#pragma unroll
  for (int mi = 0; mi < 4; ++mi) {
    const int row = row0 + wm + mi * 16 + lhi * 4;
    float4 sv = *(const float4*)(S + row);
    float sarr[4] = {sv.x, sv.y, sv.z, sv.w};
    float rs[4];
#pragma unroll
    for (int rr = 0; rr < 4; ++rr) {
      float v = 0.f;
#pragma unroll
      for (int ni = 0; ni < 4; ++ni) {
        float x2 = fmaf(acc[mi][ni][rr], INV_SCALE, muv[ni] * sarr[rr]);
        v += exp2f(x2 * BETA_LOG2E);
      }
      rs[rr] = v;
    }
#pragma unroll
    for (int m = 1; m < 16; m <<= 1) {
#pragma unroll
      for (int rr = 0; rr < 4; ++rr)
        rs[rr] += __shfl_xor(rs[rr], m, 64);
    }
    if (llo == 0) {
#pragma unroll
      for (int rr = 0; rr < 4; ++rr)
        atomicAdd(&s[row + rr], rs[rr]);
    }
  }
}

// ---- 5. out[b] = -(1/beta) * log(s[b]) ----
__global__ void finish_kernel(const float* __restrict__ s, float* __restrict__ out) {
  int b = blockIdx.x * 256 + threadIdx.x;
  out[b] = -0.1f * logf(s[b]);
}

extern "C" void kernel_launch(void* const* d_in, const int* in_sizes, int n_in,
                              void* d_out, int out_size, void* d_ws, size_t ws_size,
                              hipStream_t stream) {
  const float* g1 = (const float*)d_in[0];
  const float* W  = (const float*)d_in[1];
  float* out = (float*)d_out;

  char* ws = (char*)d_ws;
  float* s       = (float*)ws;                    // 32768*4 = 131072
  float* sq      = (float*)(ws + 131072);         // 4096*4
  float* colsum  = (float*)(ws + 147456);         // 4096*4
  float* mu      = (float*)(ws + 163840);         // 4096*4
  float* S       = (float*)(ws + 180224);         // 32768*4
  uchar_t* A8    = (uchar_t*)(ws + 311296);       // 32 MiB
  uchar_t* B8t   = (uchar_t*)(ws + 311296 + 33554432);  // 4 MiB

  hipMemsetAsync(ws, 0, 180224, stream);  // zero s, sq, colsum

  colstats<<<dim3(16, 16), 256, 0, stream>>>(W, sq, colsum);
  convert_b<<<dim3(64, 16), 256, 0, stream>>>(W, sq, colsum, B8t, mu);
  convert_a<<<dim3(2048), 256, 0, stream>>>(g1, A8, S);
  gemm_expsum<<<dim3(32, 256), 256, 0, stream>>>(A8, B8t, S, mu, s);
  finish_kernel<<<dim3(128), 256, 0, stream>>>(s, out);
}